// Round 8
// baseline (1744.808 us; speedup 1.0000x reference)
//
#include <hip/hip_runtime.h>

typedef __attribute__((ext_vector_type(8))) short short8;
typedef __attribute__((ext_vector_type(4))) float f32x4;
typedef unsigned short u16;

#define DEVI static __device__ __forceinline__

// BS=4 NQ=1024 D=256 NH=8 NP=4 L=6 DFF=1024 H=200 W=150 NV=30000 DH=32
// d_in/d_out are FP32. Internals: bf16 MFMA, fp32 accum, fp32 residual+LN.
DEVI float b2f(u16 u){ unsigned int x = ((unsigned int)u) << 16; float f; __builtin_memcpy(&f, &x, 4); return f; }
DEVI u16 f2b(float f){ unsigned int u; __builtin_memcpy(&u, &f, 4); u += 0x7fffu + ((u >> 16) & 1u); return (u16)(u >> 16); }
DEVI short8 cvt8(const float* __restrict__ p){
  f32x4 a = *(const f32x4*)p;
  f32x4 b = *(const f32x4*)(p + 4);
  short8 r;
  r[0]=(short)f2b(a[0]); r[1]=(short)f2b(a[1]); r[2]=(short)f2b(a[2]); r[3]=(short)f2b(a[3]);
  r[4]=(short)f2b(b[0]); r[5]=(short)f2b(b[1]); r[6]=(short)f2b(b[2]); r[7]=(short)f2b(b[3]);
  return r;
}

// ---------------------------------------------------------------------------
// One-shot convert/pack of ALL fp32 params -> bf16, plus obc pack, plus the
// residual-stream init (query/qpos -> out_f/out_b/qk_b). Unit = 8 elements.
// ---------------------------------------------------------------------------
__global__ __launch_bounds__(256) void cvtall_k(
    const float* __restrict__ sa_in_w, const float* __restrict__ sa_out_w,
    const float* __restrict__ val_w,   const float* __restrict__ cout_w,
    const float* __restrict__ ff1w,    const float* __restrict__ ff2w,
    const float* __restrict__ off_w,   const float* __restrict__ aw_w,
    const float* __restrict__ off_b,   const float* __restrict__ aw_b,
    const float* __restrict__ src,
    const float* __restrict__ query,   const float* __restrict__ qpos,
    u16* __restrict__ wsa_b, u16* __restrict__ wsao_b, u16* __restrict__ wval_b,
    u16* __restrict__ wcao_b, u16* __restrict__ wff1_b, u16* __restrict__ wff2_b,
    u16* __restrict__ wofaw, float* __restrict__ obc, u16* __restrict__ src_b,
    float* __restrict__ out_f, u16* __restrict__ out_b, u16* __restrict__ qk_b)
{
  long u = (long)blockIdx.x * 256 + threadIdx.x;
  if (u < 147456) { ((short8*)wsa_b)[u]  = cvt8(sa_in_w  + u * 8); return; } u -= 147456;
  if (u < 49152)  { ((short8*)wsao_b)[u] = cvt8(sa_out_w + u * 8); return; } u -= 49152;
  if (u < 49152)  { ((short8*)wval_b)[u] = cvt8(val_w    + u * 8); return; } u -= 49152;
  if (u < 49152)  { ((short8*)wcao_b)[u] = cvt8(cout_w   + u * 8); return; } u -= 49152;
  if (u < 196608) { ((short8*)wff1_b)[u] = cvt8(ff1w     + u * 8); return; } u -= 196608;
  if (u < 196608) { ((short8*)wff2_b)[u] = cvt8(ff2w     + u * 8); return; } u -= 196608;
  if (u < 12288)  { long e = u * 8; int l = (int)(e >> 14); long rem = e & 16383;
                    ((short8*)wofaw)[(l * 24576 + rem) >> 3] = cvt8(off_w + e); return; } u -= 12288;
  if (u < 6144)   { long e = u * 8; int l = (int)(e >> 13); long rem = e & 8191;
                    ((short8*)wofaw)[(l * 24576 + 16384 + rem) >> 3] = cvt8(aw_w + e); return; } u -= 6144;
  if (u < 3840000){ ((short8*)src_b)[u]  = cvt8(src + u * 8); return; } u -= 3840000;
  if (u < 72) {
    long e0 = u * 8;
#pragma unroll
    for (int j = 0; j < 8; j++) {
      long e = e0 + j;
      if (e < 384) { int l = (int)(e >> 6); obc[l * 96 + (e & 63)] = off_b[e]; }
      else { long e2 = e - 384; int l = (int)(e2 >> 5); obc[l * 96 + 64 + (e2 & 31)] = aw_b[e2]; }
    }
    return;
  } u -= 72;
  if (u < 131072) {
    long e = u * 8;
#pragma unroll
    for (int j = 0; j < 8; j++) {
      float o = query[e + j];
      out_f[e + j] = o;
      out_b[e + j] = f2b(o);
      qk_b[e + j]  = f2b(o + qpos[e + j]);
    }
  }
}

// ---------------------------------------------------------------------------
// val6_k: all 6 layers' value projections with ONE A-tile staging.
// Block = 64 rows x 256 cols; A-tile (64x256 bf16 = 32 KB) loaded to LDS once,
// then per-layer: stream W_l from L2, 128 MFMA, write 32 KB. No barrier in
// the layer loop (LDS is read-only after initial sync), so layer-l stores
// overlap layer-(l+1) MFMA.
// ---------------------------------------------------------------------------
__global__ __launch_bounds__(256) void val6_k(
    const u16* __restrict__ A,          // src_b [120000][256]
    const u16* __restrict__ W,          // wval_b [6][256][256]
    const float* __restrict__ bias,     // val_b  [6][256]
    u16* __restrict__ C)                // vsrc  [6][120000][256]
{
  __shared__ u16 As[32 * 64 * 8];
  const int wave = threadIdx.x >> 6, lane = threadIdx.x & 63;
  const int bm = blockIdx.x * 64;
  const int bn = wave * 64;
  const int lr = lane & 15, lq = lane >> 4;
#pragma unroll
  for (int it = 0; it < 8; it++) {
    int ub = wave * 512 + it * 64;
    int u = ub + lane;
    int row = u & 63, kgrp = u >> 6;
    const u16* ga = A + (long)(bm + row) * 256 + kgrp * 8;
    __builtin_amdgcn_global_load_lds(
        (const __attribute__((address_space(1))) void*)ga,
        (__attribute__((address_space(3))) void*)(As + ub * 8), 16, 0, 0);
  }
  __syncthreads();
  for (int l = 0; l < 6; l++) {
    const u16* Wl = W + (long)l * 65536;
    f32x4 acc[4][4] = {};
#pragma unroll
    for (int s = 0; s < 8; s++) {
      short8 af[4], bf[4];
#pragma unroll
      for (int i = 0; i < 4; i++)
        af[i] = *(const short8*)(As + ((s * 4 + lq) * 64 + i * 16 + lr) * 8);
#pragma unroll
      for (int j = 0; j < 4; j++) {
        int cc = bn + j * 16 + lr;
        bf[j] = *(const short8*)(Wl + (long)cc * 256 + s * 32 + lq * 8);
      }
#pragma unroll
      for (int i = 0; i < 4; i++)
#pragma unroll
        for (int j = 0; j < 4; j++)
          acc[i][j] = __builtin_amdgcn_mfma_f32_16x16x32_bf16(af[i], bf[j], acc[i][j], 0, 0, 0);
    }
    u16* Cl = C + (long)l * 30720000;
    const float* bl = bias + l * 256;
#pragma unroll
    for (int j = 0; j < 4; j++) {
      int cc = bn + j * 16 + lr;
      float bv = bl[cc];
#pragma unroll
      for (int i = 0; i < 4; i++)
#pragma unroll
        for (int r = 0; r < 4; r++) {
          int rr = bm + i * 16 + lq * 4 + r;
          Cl[(long)rr * 256 + cc] = f2b(acc[i][j][r] + bv);
        }
    }
  }
}

// ---------------------------------------------------------------------------
// gemm_w_k<MT>: MT(M) x 256(N) block; 4 waves side-by-side (wave = 64 cols).
// A chunk (MT x 256) staged in LDS via global_load_lds(16B); W streamed (L2).
// Optional RELU / bf16-out / fused V^T / fused residual+LayerNorm epilogue.
// ---------------------------------------------------------------------------
template<int MT, bool RELU, bool OUTBF, bool VT, bool LN>
__global__ __launch_bounds__(256) void gemm_w_k(
    const u16* __restrict__ A, int lda,
    const u16* __restrict__ W, long wZ,
    const float* __restrict__ bias, int bZ,
    void* __restrict__ Cv, int ldo, long cZ,
    int K,
    u16* __restrict__ vt,
    const float* __restrict__ res,
    const float* __restrict__ lnw, const float* __restrict__ lnb,
    const float* __restrict__ qpos,
    float* __restrict__ out_f, u16* __restrict__ out_b16,
    u16* __restrict__ qk_b16, float* __restrict__ hsp)
{
  __shared__ u16 As[32 * MT * 8];
  __shared__ float r1s[4][64], r2s[4][64], mArr[64], iArr[64];
  const int wave = threadIdx.x >> 6, lane = threadIdx.x & 63;
  const int bm = blockIdx.x * MT;
  const int bn = blockIdx.y * 256 + wave * 64;
  const int lr = lane & 15, lq = lane >> 4;
  constexpr int SH = (MT == 64) ? 6 : 5;
  const u16* Wz = W + (long)blockIdx.z * wZ;
  const float* bz = bias + (long)blockIdx.z * bZ;
  f32x4 acc[MT / 16][4] = {};
  const int nchunks = K >> 8;
  for (int ch = 0; ch < nchunks; ch++) {
#pragma unroll
    for (int it = 0; it < MT / 8; it++) {
      int ub = wave * (MT * 8) + it * 64;
      int u = ub + lane;
      int row = u & (MT - 1), kgrp = u >> SH;
      const u16* ga = A + (long)(bm + row) * lda + ch * 256 + kgrp * 8;
      __builtin_amdgcn_global_load_lds(
          (const __attribute__((address_space(1))) void*)ga,
          (__attribute__((address_space(3))) void*)(As + ub * 8), 16, 0, 0);
    }
    __syncthreads();
#pragma unroll
    for (int s = 0; s < 8; s++) {
      short8 af[MT / 16], bf[4];
#pragma unroll
      for (int i = 0; i < MT / 16; i++)
        af[i] = *(const short8*)(As + ((s * 4 + lq) * MT + i * 16 + lr) * 8);
#pragma unroll
      for (int j = 0; j < 4; j++) {
        int cc = bn + j * 16 + lr;
        bf[j] = *(const short8*)(Wz + (long)cc * K + ch * 256 + s * 32 + lq * 8);
      }
#pragma unroll
      for (int i = 0; i < MT / 16; i++)
#pragma unroll
        for (int j = 0; j < 4; j++)
          acc[i][j] = __builtin_amdgcn_mfma_f32_16x16x32_bf16(af[i], bf[j], acc[i][j], 0, 0, 0);
    }
    __syncthreads();
  }

  float bv[4];
#pragma unroll
  for (int j = 0; j < 4; j++) bv[j] = bz[bn + j * 16 + lr];

  if (!LN) {
    char* Cz = (char*)Cv;
#pragma unroll
    for (int j = 0; j < 4; j++) {
      int cc = bn + j * 16 + lr;
#pragma unroll
      for (int i = 0; i < MT / 16; i++) {
#pragma unroll
        for (int r = 0; r < 4; r++) {
          int rr = bm + i * 16 + lq * 4 + r;
          float v = acc[i][j][r] + bv[j];
          if (RELU) v = fmaxf(v, 0.f);
          long idx = (long)blockIdx.z * cZ + (long)rr * ldo + cc;
          if (OUTBF) ((u16*)Cz)[idx] = f2b(v);
          else       ((float*)Cz)[idx] = v;
          if (VT) {
            int b_ = rr >> 10, q_ = rr & 1023, h_ = cc >> 5, dh_ = cc & 31;
            vt[(long)((((b_ << 3) + h_) << 5) + dh_) * 1024 + q_] = f2b(v);
          }
        }
      }
    }
  } else {
    float s1[MT / 16][4] = {}, s2[MT / 16][4] = {};
#pragma unroll
    for (int i = 0; i < MT / 16; i++) {
#pragma unroll
      for (int r = 0; r < 4; r++) {
        int rowg = bm + i * 16 + lq * 4 + r;
#pragma unroll
        for (int j = 0; j < 4; j++) {
          int cc = bn + j * 16 + lr;
          float x = acc[i][j][r] + bv[j] + res[(long)rowg * 256 + cc];
          s1[i][r] += x; s2[i][r] += x * x;
        }
      }
    }
#pragma unroll
    for (int i = 0; i < MT / 16; i++)
#pragma unroll
      for (int r = 0; r < 4; r++) {
#pragma unroll
        for (int m = 1; m <= 8; m <<= 1) {
          s1[i][r] += __shfl_xor(s1[i][r], m);
          s2[i][r] += __shfl_xor(s2[i][r], m);
        }
      }
    if (lr == 0) {
#pragma unroll
      for (int i = 0; i < MT / 16; i++)
#pragma unroll
        for (int r = 0; r < 4; r++) {
          int rl = i * 16 + lq * 4 + r;
          r1s[wave][rl] = s1[i][r];
          r2s[wave][rl] = s2[i][r];
        }
    }
    __syncthreads();
    if (threadIdx.x < MT) {
      int t = threadIdx.x;
      float a = r1s[0][t] + r1s[1][t] + r1s[2][t] + r1s[3][t];
      float b = r2s[0][t] + r2s[1][t] + r2s[2][t] + r2s[3][t];
      float m = a * (1.f / 256.f);
      float var = b * (1.f / 256.f) - m * m;
      mArr[t] = m;
      iArr[t] = rsqrtf(var + 1e-5f);
    }
    __syncthreads();
#pragma unroll
    for (int i = 0; i < MT / 16; i++) {
#pragma unroll
      for (int r = 0; r < 4; r++) {
        int rl = i * 16 + lq * 4 + r;
        int rowg = bm + rl;
        float m = mArr[rl], inv = iArr[rl];
#pragma unroll
        for (int j = 0; j < 4; j++) {
          int cc = bn + j * 16 + lr;
          long idx = (long)rowg * 256 + cc;
          float x = acc[i][j][r] + bv[j] + res[idx];
          float y = (x - m) * inv * lnw[cc] + lnb[cc];
          out_f[idx] = y;
          if (out_b16) out_b16[idx] = f2b(y);
          if (qk_b16)  qk_b16[idx]  = f2b(y + qpos[idx]);
          if (hsp)     hsp[idx]     = y;
        }
      }
    }
  }
}

// ---------------------------------------------------------------------------
// qkv_k: merged Q/K/V projection. grid (64, 3): y=0 -> Q cols of qkbuf,
// y=1 -> K cols, y=2 -> V (writes vt only).
// ---------------------------------------------------------------------------
__global__ __launch_bounds__(256) void qkv_k(
    const u16* __restrict__ qk_b, const u16* __restrict__ out_b,
    const u16* __restrict__ wsa, const float* __restrict__ bsa,
    u16* __restrict__ qkbuf, u16* __restrict__ vt)
{
  __shared__ u16 As[32 * 64 * 8];
  const int sel = blockIdx.y;
  const u16* A = (sel == 2) ? out_b : qk_b;
  const u16* W = wsa + (long)sel * 256 * 256;
  const int wave = threadIdx.x >> 6, lane = threadIdx.x & 63;
  const int bm = blockIdx.x * 64;
  const int bn = wave * 64;
  const int lr = lane & 15, lq = lane >> 4;
  f32x4 acc[4][4] = {};
#pragma unroll
  for (int it = 0; it < 8; it++) {
    int ub = wave * 512 + it * 64;
    int u = ub + lane;
    int row = u & 63, kgrp = u >> 6;
    const u16* ga = A + (long)(bm + row) * 256 + kgrp * 8;
    __builtin_amdgcn_global_load_lds(
        (const __attribute__((address_space(1))) void*)ga,
        (__attribute__((address_space(3))) void*)(As + ub * 8), 16, 0, 0);
  }
  __syncthreads();
#pragma unroll
  for (int s = 0; s < 8; s++) {
    short8 af[4], bf[4];
#pragma unroll
    for (int i = 0; i < 4; i++)
      af[i] = *(const short8*)(As + ((s * 4 + lq) * 64 + i * 16 + lr) * 8);
#pragma unroll
    for (int j = 0; j < 4; j++) {
      int cc = bn + j * 16 + lr;
      bf[j] = *(const short8*)(W + (long)cc * 256 + s * 32 + lq * 8);
    }
#pragma unroll
    for (int i = 0; i < 4; i++)
#pragma unroll
      for (int j = 0; j < 4; j++)
        acc[i][j] = __builtin_amdgcn_mfma_f32_16x16x32_bf16(af[i], bf[j], acc[i][j], 0, 0, 0);
  }
  float bv[4];
#pragma unroll
  for (int j = 0; j < 4; j++) bv[j] = bsa[sel * 256 + bn + j * 16 + lr];
#pragma unroll
  for (int j = 0; j < 4; j++) {
    int cc = bn + j * 16 + lr;
#pragma unroll
    for (int i = 0; i < 4; i++) {
#pragma unroll
      for (int r = 0; r < 4; r++) {
        int rr = bm + i * 16 + lq * 4 + r;
        float v = acc[i][j][r] + bv[j];
        if (sel < 2) {
          qkbuf[(long)rr * 512 + sel * 256 + cc] = f2b(v);
        } else {
          int b_ = rr >> 10, q_ = rr & 1023, h_ = cc >> 5, dh_ = cc & 31;
          vt[(long)((((b_ << 3) + h_) << 5) + dh_) * 1024 + q_] = f2b(v);
        }
      }
    }
  }
}

// ---------------------------------------------------------------------------
// Flash self-attention: block per (b,h,q-tile 128).
// ---------------------------------------------------------------------------
__global__ __launch_bounds__(256) void flash_k(
    const u16* __restrict__ qkbuf, const u16* __restrict__ vt,
    u16* __restrict__ obuf)
{
  const float SC = 0.17677669529663687f;
  __shared__ u16 Plds[4][32][136];
  const int bh = blockIdx.x >> 3;
  const int b = bh >> 3, h = bh & 7;
  const int qt = blockIdx.x & 7;
  const int wave = threadIdx.x >> 6, lane = threadIdx.x & 63;
  const int lr = lane & 15, lq = lane >> 4;
  const int qbase = qt * 128 + wave * 32;

  short8 qf[2];
#pragma unroll
  for (int i = 0; i < 2; i++)
    qf[i] = *(const short8*)(qkbuf + (long)(b * 1024 + qbase + i * 16 + lr) * 512 + h * 32 + lq * 8);

  const u16* Kb = qkbuf + (long)b * 1024 * 512 + 256 + h * 32;
  const u16* Vb = vt + (long)bh * 32 * 1024;

  f32x4 acc_o[2][2] = {};
  float m_run[2][4], l_run[2][4];
#pragma unroll
  for (int i = 0; i < 2; i++)
#pragma unroll
    for (int r = 0; r < 4; r++){ m_run[i][r] = -3e38f; l_run[i][r] = 0.f; }

  for (int kt = 0; kt < 8; kt++) {
    f32x4 s[2][8] = {};
#pragma unroll
    for (int j = 0; j < 8; j++) {
      short8 kf = *(const short8*)(Kb + (long)(kt * 128 + j * 16 + lr) * 512 + lq * 8);
#pragma unroll
      for (int i = 0; i < 2; i++)
        s[i][j] = __builtin_amdgcn_mfma_f32_16x16x32_bf16(qf[i], kf, s[i][j], 0, 0, 0);
    }
#pragma unroll
    for (int i = 0; i < 2; i++) {
#pragma unroll
      for (int r = 0; r < 4; r++) {
        float mx = s[i][0][r];
#pragma unroll
        for (int j = 1; j < 8; j++) mx = fmaxf(mx, s[i][j][r]);
#pragma unroll
        for (int m = 1; m <= 8; m <<= 1) mx = fmaxf(mx, __shfl_xor(mx, m));
        float m_new = fmaxf(m_run[i][r], mx);
        float alpha = __expf((m_run[i][r] - m_new) * SC);
        float sum = 0.f;
        int row = i * 16 + lq * 4 + r;
#pragma unroll
        for (int j = 0; j < 8; j++) {
          float p = __expf((s[i][j][r] - m_new) * SC);
          sum += p;
          Plds[wave][row][j * 16 + lr] = f2b(p);
        }
#pragma unroll
        for (int m = 1; m <= 8; m <<= 1) sum += __shfl_xor(sum, m);
        l_run[i][r] = l_run[i][r] * alpha + sum;
        m_run[i][r] = m_new;
#pragma unroll
        for (int d = 0; d < 2; d++) acc_o[i][d][r] *= alpha;
      }
    }
#pragma unroll
    for (int kc = 0; kc < 4; kc++) {
      short8 pf[2];
#pragma unroll
      for (int i = 0; i < 2; i++)
        pf[i] = *(const short8*)&Plds[wave][i * 16 + lr][kc * 32 + lq * 8];
#pragma unroll
      for (int d = 0; d < 2; d++) {
        short8 vf = *(const short8*)(Vb + (long)(d * 16 + lr) * 1024 + kt * 128 + kc * 32 + lq * 8);
#pragma unroll
        for (int i = 0; i < 2; i++)
          acc_o[i][d] = __builtin_amdgcn_mfma_f32_16x16x32_bf16(pf[i], vf, acc_o[i][d], 0, 0, 0);
      }
    }
  }
#pragma unroll
  for (int i = 0; i < 2; i++) {
#pragma unroll
    for (int r = 0; r < 4; r++) {
      float inv = 1.f / l_run[i][r];
      int q = qbase + i * 16 + lq * 4 + r;
#pragma unroll
      for (int d = 0; d < 2; d++)
        obuf[(long)(b * 1024 + q) * 256 + h * 32 + d * 16 + lr] = f2b(acc_o[i][d][r] * inv);
    }
  }
}

// ---------------------------------------------------------------------------
// gemm64_k (bf16-only): 64x64 block, direct loads. Used for offaw (N=96).
// ---------------------------------------------------------------------------
__global__ __launch_bounds__(256) void gemm64_k(
    const u16* __restrict__ A, int lda,
    const u16* __restrict__ W, int ldw,
    const float* __restrict__ bias,
    float* __restrict__ C, int ldo,
    int M, int N, int K)
{
  const int wave = threadIdx.x >> 6, lane = threadIdx.x & 63;
  const int wm = wave >> 1, wn = wave & 1;
  const int bm = blockIdx.x * 64 + wm * 32;
  const int bn = blockIdx.y * 64 + wn * 32;
  const int lr = lane & 15, lq = lane >> 4;
  const int koff = lq * 8;
  f32x4 acc[2][2] = {};
  const short8 Z8 = {0,0,0,0,0,0,0,0};
  for (int k0 = 0; k0 < K; k0 += 32) {
    short8 af[2], bf[2];
#pragma unroll
    for (int i = 0; i < 2; i++) {
      int r = bm + i * 16 + lr;
      af[i] = (r < M) ? *(const short8*)(A + (long)r * lda + k0 + koff) : Z8;
    }
#pragma unroll
    for (int j = 0; j < 2; j++) {
      int c = bn + j * 16 + lr;
      bf[j] = (c < N) ? *(const short8*)(W + (long)c * ldw + k0 + koff) : Z8;
    }
#pragma unroll
    for (int i = 0; i < 2; i++)
#pragma unroll
      for (int j = 0; j < 2; j++)
        acc[i][j] = __builtin_amdgcn_mfma_f32_16x16x32_bf16(af[i], bf[j], acc[i][j], 0, 0, 0);
  }
#pragma unroll
  for (int j = 0; j < 2; j++) {
    int cc = bn + j * 16 + lr;
    if (cc >= N) continue;
    float bv = bias[cc];
#pragma unroll
    for (int i = 0; i < 2; i++) {
#pragma unroll
      for (int r = 0; r < 4; r++) {
        int rr = bm + i * 16 + lq * 4 + r;
        if (rr >= M) continue;
        C[(long)rr * ldo + cc] = acc[i][j][r] + bv;
      }
    }
  }
}

__global__ __launch_bounds__(256) void msda_k(
    const float* __restrict__ refp,
    const float* __restrict__ off, int ldoff,
    const float* __restrict__ aw, int ldaw,
    const u16* __restrict__ v,
    u16* __restrict__ o,
    long vstride)
{
  int tid = blockIdx.x * 256 + threadIdx.x;
  int dh = tid & 31;
  int h  = (tid >> 5) & 7;
  int bq = tid >> 8;
  int b  = bq >> 10;
  float rx = refp[bq * 2 + 0];
  float ry = refp[bq * 2 + 1];
  const float* offp = off + (long)bq * ldoff + h * 8;
  const float* awp  = aw  + (long)bq * ldaw + h * 4;
  float a0 = awp[0], a1 = awp[1], a2 = awp[2], a3 = awp[3];
  float am = fmaxf(fmaxf(a0, a1), fmaxf(a2, a3));
  float e[4];
  e[0] = __expf(a0 - am); e[1] = __expf(a1 - am); e[2] = __expf(a2 - am); e[3] = __expf(a3 - am);
  float einv = 1.f / (e[0] + e[1] + e[2] + e[3]);
  const u16* vb = v + b * vstride + h * 32 + dh;
  float accv = 0.f;
#pragma unroll
  for (int pp = 0; pp < 4; pp++){
    float x = rx * 150.f + offp[pp * 2 + 0] - 0.5f;
    float y = ry * 200.f + offp[pp * 2 + 1] - 0.5f;
    float x0 = floorf(x), y0 = floorf(y);
    float s = 0.f;
#pragma unroll
    for (int c = 0; c < 4; c++){
      int dx = c & 1, dy = c >> 1;
      float xi = x0 + dx, yi = y0 + dy;
      float wt = (1.f - fabsf(x - xi)) * (1.f - fabsf(y - yi));
      if (xi >= 0.f && xi < 150.f && yi >= 0.f && yi < 200.f && wt > 0.f) {
        int xc = (int)xi, yc = (int)yi;
        s += wt * b2f(vb[((long)yc * 150 + xc) * 256]);
      }
    }
    accv += e[pp] * einv * s;
  }
  o[(long)bq * 256 + h * 32 + dh] = f2b(accv);
}

__global__ __launch_bounds__(256) void refs_k(const float* __restrict__ r, float* __restrict__ dst){
  int i = blockIdx.x * 256 + threadIdx.x;
  dst[i] = r[i & 8191];
}

// ---------------------------------------------------------------------------
extern "C" void kernel_launch(void* const* d_in, const int* in_sizes, int n_in,
                              void* d_out, int out_size, void* d_ws, size_t ws_size,
                              hipStream_t stream)
{
  (void)in_sizes; (void)n_in; (void)out_size;
  const float* query = (const float*)d_in[0];
  const float* qpos  = (const float*)d_in[1];
  const float* refp  = (const float*)d_in[2];
  const float* src   = (const float*)d_in[3];
  const float* sa_in_w  = (const float*)d_in[6];
  const float* sa_in_b  = (const float*)d_in[7];
  const float* sa_out_w = (const float*)d_in[8];
  const float* sa_out_b = (const float*)d_in[9];
  const float* off_w = (const float*)d_in[10];
  const float* off_b = (const float*)d_in[11];
  const float* aw_w  = (const float*)d_in[12];
  const float* aw_b  = (const float*)d_in[13];
  const float* val_w = (const float*)d_in[14];
  const float* val_b = (const float*)d_in[15];
  const float* cout_w = (const float*)d_in[16];
  const float* cout_b = (const float*)d_in[17];
  const float* n1w = (const float*)d_in[18]; const float* n1b = (const float*)d_in[19];
  const float* n2w = (const float*)d_in[20]; const float* n2b = (const float*)d_in[21];
  const float* n3w = (const float*)d_in[22]; const float* n3b = (const float*)d_in[23];
  const float* ff1w = (const float*)d_in[24]; const float* ff1b = (const float*)d_in[25];
  const float* ff2w = (const float*)d_in[26]; const float* ff2b = (const float*)d_in[27];

  float* hs = (float*)d_out;
  float* refs_out = hs + (long)6 * 4096 * 256;

  char* p = (char*)d_ws;
  auto alloc = [&](size_t bytes){ char* r = p; p += (bytes + 255) & ~(size_t)255; return r; };
  float* out_f = (float*)alloc(4194304);
  u16*   qk_b  = (u16*)  alloc(2097152);
  u16*   out_b = (u16*)  alloc(2097152);
  u16* wsa_b  = (u16*)alloc(2359296);
  u16* wsao_b = (u16*)alloc(786432);
  u16* wofaw  = (u16*)alloc(294912);
  u16* wval_b = (u16*)alloc(786432);
  u16* wcao_b = (u16*)alloc(786432);
  u16* wff1_b = (u16*)alloc(3145728);
  u16* wff2_b = (u16*)alloc(3145728);
  float* obc  = (float*)alloc(2304);
  u16* src_b  = (u16*)alloc(61440000);
  u16* qkbuf  = (u16*)alloc(4194304);
  u16* vt     = (u16*)alloc(2097152);
  u16* obuf   = (u16*)alloc(2097152);
  float* oawo = (float*)alloc(1572864);
  u16* mo     = (u16*)alloc(2097152);
  u16* ffh    = (u16*)alloc(8388608);
  size_t used = (size_t)(p - (char*)d_ws);
  const bool big = (ws_size >= used + 368640000ull);   // room for 6-layer vsrc
  u16* vsrc = (u16*)alloc(big ? 368640000ull : 61440000ull);

  // converts + packs + residual init, one launch
  cvtall_k<<<18273, 256, 0, stream>>>(sa_in_w, sa_out_w, val_w, cout_w, ff1w, ff2w,
                                      off_w, aw_w, off_b, aw_b, src, query, qpos,
                                      wsa_b, wsao_b, wval_b, wcao_b, wff1_b, wff2_b,
                                      wofaw, obc, src_b, out_f, out_b, qk_b);
  if (big) {
    // all 6 layers' value projections; A-tile staged ONCE per block
    val6_k<<<1875, 256, 0, stream>>>(src_b, wval_b, val_b, vsrc);
  }

  for (int l = 0; l < 6; l++){
    const u16* wsa = wsa_b + (long)l * 768 * 256;
    // ---- self attention (flash) ----
    qkv_k<<<dim3(64,3,1),256,0,stream>>>(qk_b, out_b, wsa, sa_in_b + l * 768, qkbuf, vt);
    flash_k<<<256,256,0,stream>>>(qkbuf, vt, obuf);
    gemm_w_k<32,false,false,false,true><<<dim3(128,1,1),256,0,stream>>>(   // out-proj + norm2
        obuf, 256, wsao_b + (long)l*65536, 0, sa_out_b + l*256, 0, nullptr, 0, 0, 256,
        nullptr, out_f, n2w + l*256, n2b + l*256, qpos, out_f, nullptr, qk_b, nullptr);
    // ---- deformable cross attention ----
    gemm64_k<<<dim3(64,2,1),256,0,stream>>>(qk_b, 256, wofaw + (long)l*24576, 256,
        obc + l*96, oawo, 96, 4096, 96, 256);
    if (!big) {
      gemm_w_k<64,false,true,false,false><<<dim3(1875,1,1),256,0,stream>>>(
          src_b, 256, wval_b + (long)l*65536, 0, val_b + l*256, 0, vsrc, 256, 0, 256,
          nullptr, nullptr,nullptr,nullptr,nullptr,nullptr,nullptr,nullptr,nullptr);
    }
    const u16* vsl = big ? (vsrc + (long)l*30720000) : vsrc;
    msda_k<<<4096,256,0,stream>>>(refp, oawo, 96, oawo + 64, 96, vsl, mo, 7680000);
    gemm_w_k<32,false,false,false,true><<<dim3(128,1,1),256,0,stream>>>(   // ca-out + norm1
        mo, 256, wcao_b + (long)l*65536, 0, cout_b + l*256, 0, nullptr, 0, 0, 256,
        nullptr, out_f, n1w + l*256, n1b + l*256, nullptr, out_f, out_b, nullptr, nullptr);
    // ---- ffn ----
    gemm_w_k<32,true,true,false,false><<<dim3(128,4,1),256,0,stream>>>(    // ff1 + relu
        out_b, 256, wff1_b + (long)l*262144, 0, ff1b + l*1024, 0, ffh, 1024, 0, 256,
        nullptr, nullptr,nullptr,nullptr,nullptr,nullptr,nullptr,nullptr,nullptr);
    gemm_w_k<32,false,false,false,true><<<dim3(128,1,1),256,0,stream>>>(   // ff2 + norm3
        ffh, 1024, wff2_b + (long)l*262144, 0, ff2b + l*256, 0, nullptr, 0, 0, 1024,
        nullptr, out_f, n3w + l*256, n3b + l*256, qpos, out_f, out_b, qk_b,
        hs + (long)l*1048576);
  }
  refs_k<<<192,256,0,stream>>>(refp, refs_out);
}